// Round 1
// baseline (275.109 us; speedup 1.0000x reference)
//
#include <hip/hip_runtime.h>
#include <hip/hip_bf16.h>

typedef __attribute__((ext_vector_type(4))) float f32x4;
typedef __attribute__((ext_vector_type(8))) short short8;
typedef unsigned short u16;

#define NROWS 8192
#define DM 1024
#define EPSF 1e-8f

static __device__ __forceinline__ u16 f2bf(float x) {
  unsigned u = __float_as_uint(x);
  u += 0x7fffu + ((u >> 16) & 1u);   // RNE
  return (u16)(u >> 16);
}

// insert v into descending-sorted S[8] (registers only; fully unrolled)
static __device__ __forceinline__ void topk_insert(float (&S)[8], float v) {
  if (v <= S[7]) return;
  S[7] = v;
#pragma unroll
  for (int q = 7; q > 0; --q) {
    float a = S[q - 1], b = S[q];
    S[q - 1] = fmaxf(a, b);
    S[q]     = fminf(a, b);
  }
}

// ---------------- kernel 1: row norm -> bf16 F, content logits ----------------
__global__ __launch_bounds__(256) void k_rowprep(
    const float* __restrict__ H, const float* __restrict__ Wc,
    const float* __restrict__ bc, u16* __restrict__ F, float* __restrict__ CL)
{
  const int r = blockIdx.x;
  const int t = threadIdx.x;
  const int lane = t & 63;
  const int w = t >> 6;

  const float4 h  = ((const float4*)(H  + (size_t)r * DM))[t];
  const float4 c0 = ((const float4*)(Wc + 0 * DM))[t];
  const float4 c1 = ((const float4*)(Wc + 1 * DM))[t];
  const float4 c2 = ((const float4*)(Wc + 2 * DM))[t];

  float ss = h.x*h.x + h.y*h.y + h.z*h.z + h.w*h.w;
  float d0 = h.x*c0.x + h.y*c0.y + h.z*c0.z + h.w*c0.w;
  float d1 = h.x*c1.x + h.y*c1.y + h.z*c1.z + h.w*c1.w;
  float d2 = h.x*c2.x + h.y*c2.y + h.z*c2.z + h.w*c2.w;

#pragma unroll
  for (int off = 32; off > 0; off >>= 1) {
    ss += __shfl_down(ss, off);
    d0 += __shfl_down(d0, off);
    d1 += __shfl_down(d1, off);
    d2 += __shfl_down(d2, off);
  }
  __shared__ float red[4][4];
  __shared__ float bcast;
  if (lane == 0) { red[w][0] = ss; red[w][1] = d0; red[w][2] = d1; red[w][3] = d2; }
  __syncthreads();
  if (t == 0) {
    float S  = red[0][0] + red[1][0] + red[2][0] + red[3][0];
    float D0 = red[0][1] + red[1][1] + red[2][1] + red[3][1];
    float D1 = red[0][2] + red[1][2] + red[2][2] + red[3][2];
    float D2 = red[0][3] + red[1][3] + red[2][3] + red[3][3];
    bcast = 1.0f / (sqrtf(S) + EPSF);
    CL[r*3+0] = D0 + bc[0];
    CL[r*3+1] = D1 + bc[1];
    CL[r*3+2] = D2 + bc[2];
  }
  __syncthreads();
  const float invn = bcast;
  ushort4 o;
  o.x = f2bf(h.x * invn); o.y = f2bf(h.y * invn);
  o.z = f2bf(h.z * invn); o.w = f2bf(h.w * invn);
  ((ushort4*)(F + (size_t)r * DM))[t] = o;
}

// ---------------- kernel 2: sim GEMM (bf16 MFMA) fused with top-8 ----------------
// grid (64 rowblocks of 128, 8 colsplits of 1024). 256 threads = 4 waves.
// wave w: rows (w>>1)*64.., cols (w&1)*64.. of the 128x128 tile, 4x4 frags of 16x16x32.
__global__ __launch_bounds__(256, 2) void k_simtopk(
    const u16* __restrict__ F, float* __restrict__ partials)
{
  __shared__ char smem[64 * 129 * 4];      // 33024 B, unioned
  u16*   As = (u16*)smem;                  // [128][32] bf16
  u16*   Bs = (u16*)(smem + 8192);         // [128][32] bf16
  float* Cs = (float*)smem;                // [64][129] f32 (half-tile)
  float* Ms = (float*)smem;                // [128][32] merge buffer

  const int t    = threadIdx.x;
  const int lane = t & 63;
  const int w    = t >> 6;
  const int wr   = (w >> 1) * 64;
  const int wc   = (w & 1) * 64;
  const int R0    = blockIdx.x * 128;
  const int CBASE = blockIdx.y * 1024;

  float sA[8], sB[8];
#pragma unroll
  for (int q = 0; q < 8; ++q) { sA[q] = -1e30f; sB[q] = -1e30f; }

  const int srow = t & 63;   // scan row within 64-row half
  const int scol = w * 32;   // scan col base (wave = col quarter)

  for (int ct = 0; ct < 8; ++ct) {
    const int C0 = CBASE + ct * 128;
    f32x4 acc[4][4];
#pragma unroll
    for (int i = 0; i < 4; ++i)
#pragma unroll
      for (int j = 0; j < 4; ++j)
        acc[i][j] = {0.f, 0.f, 0.f, 0.f};

    for (int kk = 0; kk < 32; ++kk) {
      const int k0 = kk * 32;
#pragma unroll
      for (int hh = 0; hh < 2; ++hh) {
        const int idx = t + hh * 256;
        const int row = idx >> 2;
        const int ch  = idx & 3;
        *(uint4*)(As + row * 32 + ch * 8) =
            *(const uint4*)(F + (size_t)(R0 + row) * DM + k0 + ch * 8);
        *(uint4*)(Bs + row * 32 + ch * 8) =
            *(const uint4*)(F + (size_t)(C0 + row) * DM + k0 + ch * 8);
      }
      __syncthreads();
      short8 a[4], b[4];
#pragma unroll
      for (int i = 0; i < 4; ++i)
        a[i] = *(const short8*)(As + (wr + i * 16 + (lane & 15)) * 32 + (lane >> 4) * 8);
#pragma unroll
      for (int j = 0; j < 4; ++j)
        b[j] = *(const short8*)(Bs + (wc + j * 16 + (lane & 15)) * 32 + (lane >> 4) * 8);
#pragma unroll
      for (int i = 0; i < 4; ++i)
#pragma unroll
        for (int j = 0; j < 4; ++j)
          acc[i][j] = __builtin_amdgcn_mfma_f32_16x16x32_bf16(a[i], b[j], acc[i][j], 0, 0, 0);
      __syncthreads();
    }

    // spill + scan, one 64-row half at a time (C/D layout: col=lane&15, row=(lane>>4)*4+reg)
#pragma unroll
    for (int half = 0; half < 2; ++half) {
      if ((w >> 1) == half) {
#pragma unroll
        for (int i = 0; i < 4; ++i)
#pragma unroll
          for (int j = 0; j < 4; ++j)
#pragma unroll
            for (int q = 0; q < 4; ++q) {
              const int rr = i * 16 + (lane >> 4) * 4 + q;  // 0..63 local
              const int cc = wc + j * 16 + (lane & 15);
              Cs[rr * 129 + cc] = acc[i][j][q];
            }
      }
      __syncthreads();
      const int gi = R0 + half * 64 + srow;
      if (half == 0) {
        for (int cc = 0; cc < 32; ++cc) {
          const float v = Cs[srow * 129 + scol + cc];
          if (C0 + scol + cc != gi) topk_insert(sA, v);
        }
      } else {
        for (int cc = 0; cc < 32; ++cc) {
          const float v = Cs[srow * 129 + scol + cc];
          if (C0 + scol + cc != gi) topk_insert(sB, v);
        }
      }
      __syncthreads();
    }
  }

  // merge the 4 col-quarter lists per row -> top-8 partial for this colsplit
#pragma unroll
  for (int q = 0; q < 8; ++q) {
    Ms[(srow)      * 32 + w * 8 + q] = sA[q];
    Ms[(64 + srow) * 32 + w * 8 + q] = sB[q];
  }
  __syncthreads();
  if (t < 128) {
    unsigned m = 0;
    float* dst = partials + (size_t)(R0 + t) * 64 + blockIdx.y * 8;
    for (int q = 0; q < 8; ++q) {
      float best = -1e30f; int bj = 0;
      for (int jj = 0; jj < 32; ++jj) {
        const float v = Ms[t * 32 + jj];
        if (!((m >> jj) & 1u) && v > best) { best = v; bj = jj; }
      }
      m |= 1u << bj;
      dst[q] = best;  // descending
    }
  }
}

// ---------------- kernel 3: merge partials, features, MLP, mix, softmax ----------------
__global__ __launch_bounds__(256) void k_finalize(
    const float* __restrict__ partials, const float* __restrict__ CL,
    const float* __restrict__ W1, const float* __restrict__ b1,
    const float* __restrict__ W2, const float* __restrict__ b2,
    const float* __restrict__ alpha, float* __restrict__ out)
{
  const int n = blockIdx.x * 256 + threadIdx.x;
  if (n >= NROWS) return;
  const float* p = partials + (size_t)n * 64;
  unsigned long long mask = 0ull;
  float sum = 0.f, sumsq = 0.f, mins = 0.f;
  for (int q = 0; q < 8; ++q) {
    float best = -1e30f; int bj = 0;
    for (int jj = 0; jj < 64; ++jj) {
      const float v = p[jj];
      if (!((mask >> jj) & 1ull) && v > best) { best = v; bj = jj; }
    }
    mask |= 1ull << bj;
    sum += best; sumsq += best * best; mins = best;
  }
  // knn_dists d = 1 - s ; std/mean invariant transforms
  const float mean_s  = sum * 0.125f;
  float var = (sumsq - 8.f * mean_s * mean_s) * (1.f / 7.f);  // ddof=1
  var = fmaxf(var, 0.f);
  const float tree    = sqrtf(var);
  const float density = 1.f - mean_s;
  const float outlier = (1.f - mins) / (density + EPSF);

  float a0 = b2[0], a1 = b2[1], a2 = b2[2];
#pragma unroll
  for (int j = 0; j < 32; ++j) {
    float hj = W1[j*3+0]*tree + W1[j*3+1]*density + W1[j*3+2]*outlier + b1[j];
    hj = fmaxf(hj, 0.f);
    a0 += W2[j]      * hj;
    a1 += W2[32 + j] * hj;
    a2 += W2[64 + j] * hj;
  }
  const float mix = 1.f / (1.f + expf(-alpha[0]));
  const float im  = 1.f - mix;
  const float l0 = mix * CL[n*3+0] + im * a0;
  const float l1 = mix * CL[n*3+1] + im * a1;
  const float l2 = mix * CL[n*3+2] + im * a2;
  const float mx = fmaxf(l0, fmaxf(l1, l2));
  const float e0 = expf(l0 - mx), e1 = expf(l1 - mx), e2 = expf(l2 - mx);
  const float inv = 1.f / (e0 + e1 + e2);
  out[n*3+0] = e0 * inv;
  out[n*3+1] = e1 * inv;
  out[n*3+2] = e2 * inv;
  float* outl = out + NROWS * 3;
  outl[n*3+0] = l0;
  outl[n*3+1] = l1;
  outl[n*3+2] = l2;
}

extern "C" void kernel_launch(void* const* d_in, const int* in_sizes, int n_in,
                              void* d_out, int out_size, void* d_ws, size_t ws_size,
                              hipStream_t stream) {
  const float* H     = (const float*)d_in[0];
  const float* Wc    = (const float*)d_in[1];
  const float* bc    = (const float*)d_in[2];
  const float* W1    = (const float*)d_in[3];
  const float* b1    = (const float*)d_in[4];
  const float* W2    = (const float*)d_in[5];
  const float* b2    = (const float*)d_in[6];
  const float* alpha = (const float*)d_in[7];
  float* out = (float*)d_out;

  char* ws = (char*)d_ws;
  u16*   F        = (u16*)ws;                               // 8192*1024*2  = 16 MiB
  float* CL       = (float*)(ws + 16777216);                // 8192*3*4     = 96 KiB
  float* partials = (float*)(ws + 16777216 + 98304);        // 8192*64*4    = 2 MiB

  k_rowprep<<<NROWS, 256, 0, stream>>>(H, Wc, bc, F, CL);
  dim3 g2(64, 8);
  k_simtopk<<<g2, 256, 0, stream>>>(F, partials);
  k_finalize<<<NROWS / 256, 256, 0, stream>>>(partials, CL, W1, b1, W2, b2, alpha, out);
}

// Round 2
// 228.225 us; speedup vs baseline: 1.2054x; 1.2054x over previous
//
#include <hip/hip_runtime.h>
#include <hip/hip_bf16.h>

typedef __attribute__((ext_vector_type(4))) float f32x4;
typedef __attribute__((ext_vector_type(8))) short short8;
typedef unsigned short u16;

#define NROWS 8192
#define DM 1024
#define EPSF 1e-8f

// async global->LDS, 16B per lane, wave-uniform LDS base (rule #21: linear dest,
// inverse-swizzled SOURCE, swizzle applied again on the ds_read side)
#define GLDS(gsrc, ldst) __builtin_amdgcn_global_load_lds(                 \
    (const __attribute__((address_space(1))) void*)(gsrc),                 \
    (__attribute__((address_space(3))) void*)(ldst), 16, 0, 0)

static __device__ __forceinline__ u16 f2bf(float x) {
  unsigned u = __float_as_uint(x);
  u += 0x7fffu + ((u >> 16) & 1u);   // RNE
  return (u16)(u >> 16);
}

// insert v into descending-sorted S[8] (registers only; fully unrolled)
static __device__ __forceinline__ void topk_insert(float (&S)[8], float v) {
  if (v <= S[7]) return;
  S[7] = v;
#pragma unroll
  for (int q = 7; q > 0; --q) {
    float a = S[q - 1], b = S[q];
    S[q - 1] = fmaxf(a, b);
    S[q]     = fminf(a, b);
  }
}

// ---------------- kernel 1: row norm -> bf16 F, content logits ----------------
__global__ __launch_bounds__(256) void k_rowprep(
    const float* __restrict__ H, const float* __restrict__ Wc,
    const float* __restrict__ bc, u16* __restrict__ F, float* __restrict__ CL)
{
  const int r = blockIdx.x;
  const int t = threadIdx.x;
  const int lane = t & 63;
  const int w = t >> 6;

  const float4 h  = ((const float4*)(H  + (size_t)r * DM))[t];
  const float4 c0 = ((const float4*)(Wc + 0 * DM))[t];
  const float4 c1 = ((const float4*)(Wc + 1 * DM))[t];
  const float4 c2 = ((const float4*)(Wc + 2 * DM))[t];

  float ss = h.x*h.x + h.y*h.y + h.z*h.z + h.w*h.w;
  float d0 = h.x*c0.x + h.y*c0.y + h.z*c0.z + h.w*c0.w;
  float d1 = h.x*c1.x + h.y*c1.y + h.z*c1.z + h.w*c1.w;
  float d2 = h.x*c2.x + h.y*c2.y + h.z*c2.z + h.w*c2.w;

#pragma unroll
  for (int off = 32; off > 0; off >>= 1) {
    ss += __shfl_down(ss, off);
    d0 += __shfl_down(d0, off);
    d1 += __shfl_down(d1, off);
    d2 += __shfl_down(d2, off);
  }
  __shared__ float red[4][4];
  __shared__ float bcast;
  if (lane == 0) { red[w][0] = ss; red[w][1] = d0; red[w][2] = d1; red[w][3] = d2; }
  __syncthreads();
  if (t == 0) {
    float S  = red[0][0] + red[1][0] + red[2][0] + red[3][0];
    float D0 = red[0][1] + red[1][1] + red[2][1] + red[3][1];
    float D1 = red[0][2] + red[1][2] + red[2][2] + red[3][2];
    float D2 = red[0][3] + red[1][3] + red[2][3] + red[3][3];
    bcast = 1.0f / (sqrtf(S) + EPSF);
    CL[r*3+0] = D0 + bc[0];
    CL[r*3+1] = D1 + bc[1];
    CL[r*3+2] = D2 + bc[2];
  }
  __syncthreads();
  const float invn = bcast;
  ushort4 o;
  o.x = f2bf(h.x * invn); o.y = f2bf(h.y * invn);
  o.z = f2bf(h.z * invn); o.w = f2bf(h.w * invn);
  ((ushort4*)(F + (size_t)r * DM))[t] = o;
}

// ---------------- kernel 2: sim GEMM (bf16 MFMA) fused with top-8 ----------------
// grid (64 rowblocks of 128, 8 colsplits of 1024). 256 threads = 4 waves.
// BK=64 (128B rows = 8 x 16B chunks), XOR chunk swizzle c ^= row&7 on both sides.
__global__ __launch_bounds__(256, 2) void k_simtopk(
    const u16* __restrict__ F, float* __restrict__ partials)
{
  __shared__ char smem[33280];
  u16*   As = (u16*)smem;                  // [128][64] bf16 (swizzled chunks), 16 KiB
  u16*   Bs = (u16*)(smem + 16384);        // [128][64] bf16, 16 KiB
  float* Cs = (float*)smem;                // [64][129] f32 half-tile spill (33024 B)
  float* Ms = (float*)smem;                // [128][32] merge buffer

  const int t    = threadIdx.x;
  const int lane = t & 63;
  const int w    = t >> 6;
  const int wr   = (w >> 1) * 64;
  const int wc   = (w & 1) * 64;
  const int R0    = blockIdx.x * 128;
  const int CBASE = blockIdx.y * 1024;
  const int wchunk = t & 192;              // wave-uniform chunk base within 256

  float sA[8], sB[8];
#pragma unroll
  for (int q = 0; q < 8; ++q) { sA[q] = -1e30f; sB[q] = -1e30f; }

  const int srow = t & 63;   // scan row within 64-row half
  const int scol = w * 32;   // scan col base (wave = col quarter)

  // per-thread inverse-swizzled staging source (row, k-chunk) — kk-invariant
  int strow[4], stkc[4];
#pragma unroll
  for (int it = 0; it < 4; ++it) {
    const int p = it * 256 + t;            // chunk id 0..1023
    strow[it] = p >> 3;
    stkc[it]  = ((p & 7) ^ ((p >> 3) & 7)) * 8;   // u16 offset within 64
  }

  for (int ct = 0; ct < 8; ++ct) {
    const int C0 = CBASE + ct * 128;
    f32x4 acc[4][4];
#pragma unroll
    for (int i = 0; i < 4; ++i)
#pragma unroll
      for (int j = 0; j < 4; ++j)
        acc[i][j] = {0.f, 0.f, 0.f, 0.f};

    for (int kk = 0; kk < 16; ++kk) {
      const int k0 = kk * 64;
#pragma unroll
      for (int it = 0; it < 4; ++it) {
        GLDS(F + (size_t)(R0 + strow[it]) * DM + k0 + stkc[it],
             smem + (it * 256 + wchunk) * 16);
        GLDS(F + (size_t)(C0 + strow[it]) * DM + k0 + stkc[it],
             smem + 16384 + (it * 256 + wchunk) * 16);
      }
      __syncthreads();   // compiler drains vmcnt(0) here
#pragma unroll
      for (int ks = 0; ks < 2; ++ks) {
        short8 a[4], b[4];
#pragma unroll
        for (int i = 0; i < 4; ++i) {
          const int row = wr + i * 16 + (lane & 15);
          const int c   = (ks * 4 + (lane >> 4)) ^ (lane & 7);
          a[i] = *(const short8*)(As + row * 64 + c * 8);
        }
#pragma unroll
        for (int j = 0; j < 4; ++j) {
          const int row = wc + j * 16 + (lane & 15);
          const int c   = (ks * 4 + (lane >> 4)) ^ (lane & 7);
          b[j] = *(const short8*)(Bs + row * 64 + c * 8);
        }
#pragma unroll
        for (int i = 0; i < 4; ++i)
#pragma unroll
          for (int j = 0; j < 4; ++j)
            acc[i][j] = __builtin_amdgcn_mfma_f32_16x16x32_bf16(a[i], b[j], acc[i][j], 0, 0, 0);
      }
      __syncthreads();
    }

    // spill + scan, one 64-row half at a time (C/D layout: col=lane&15, row=(lane>>4)*4+reg)
#pragma unroll
    for (int half = 0; half < 2; ++half) {
      if ((w >> 1) == half) {
#pragma unroll
        for (int i = 0; i < 4; ++i)
#pragma unroll
          for (int j = 0; j < 4; ++j)
#pragma unroll
            for (int q = 0; q < 4; ++q) {
              const int rr = i * 16 + (lane >> 4) * 4 + q;  // 0..63 local
              const int cc = wc + j * 16 + (lane & 15);
              Cs[rr * 129 + cc] = acc[i][j][q];
            }
      }
      __syncthreads();
      const int gi = R0 + half * 64 + srow;
      if (half == 0) {
        for (int cc = 0; cc < 32; ++cc) {
          const float v = Cs[srow * 129 + scol + cc];
          if (C0 + scol + cc != gi) topk_insert(sA, v);
        }
      } else {
        for (int cc = 0; cc < 32; ++cc) {
          const float v = Cs[srow * 129 + scol + cc];
          if (C0 + scol + cc != gi) topk_insert(sB, v);
        }
      }
      __syncthreads();
    }
  }

  // merge the 4 col-quarter lists per row -> top-8 partial for this colsplit
#pragma unroll
  for (int q = 0; q < 8; ++q) {
    Ms[(srow)      * 32 + w * 8 + q] = sA[q];
    Ms[(64 + srow) * 32 + w * 8 + q] = sB[q];
  }
  __syncthreads();
  if (t < 128) {
    unsigned m = 0;
    float* dst = partials + (size_t)(R0 + t) * 64 + blockIdx.y * 8;
    for (int q = 0; q < 8; ++q) {
      float best = -1e30f; int bj = 0;
      for (int jj = 0; jj < 32; ++jj) {
        const float v = Ms[t * 32 + jj];
        if (!((m >> jj) & 1u) && v > best) { best = v; bj = jj; }
      }
      m |= 1u << bj;
      dst[q] = best;  // descending
    }
  }
}

// ---------------- kernel 3: merge partials, features, MLP, mix, softmax ----------------
__global__ __launch_bounds__(256) void k_finalize(
    const float* __restrict__ partials, const float* __restrict__ CL,
    const float* __restrict__ W1, const float* __restrict__ b1,
    const float* __restrict__ W2, const float* __restrict__ b2,
    const float* __restrict__ alpha, float* __restrict__ out)
{
  const int n = blockIdx.x * 256 + threadIdx.x;
  if (n >= NROWS) return;
  const float* p = partials + (size_t)n * 64;
  unsigned long long mask = 0ull;
  float sum = 0.f, sumsq = 0.f, mins = 0.f;
  for (int q = 0; q < 8; ++q) {
    float best = -1e30f; int bj = 0;
    for (int jj = 0; jj < 64; ++jj) {
      const float v = p[jj];
      if (!((mask >> jj) & 1ull) && v > best) { best = v; bj = jj; }
    }
    mask |= 1ull << bj;
    sum += best; sumsq += best * best; mins = best;
  }
  const float mean_s  = sum * 0.125f;
  float var = (sumsq - 8.f * mean_s * mean_s) * (1.f / 7.f);  // ddof=1
  var = fmaxf(var, 0.f);
  const float tree    = sqrtf(var);
  const float density = 1.f - mean_s;
  const float outlier = (1.f - mins) / (density + EPSF);

  float a0 = b2[0], a1 = b2[1], a2 = b2[2];
#pragma unroll
  for (int j = 0; j < 32; ++j) {
    float hj = W1[j*3+0]*tree + W1[j*3+1]*density + W1[j*3+2]*outlier + b1[j];
    hj = fmaxf(hj, 0.f);
    a0 += W2[j]      * hj;
    a1 += W2[32 + j] * hj;
    a2 += W2[64 + j] * hj;
  }
  const float mix = 1.f / (1.f + expf(-alpha[0]));
  const float im  = 1.f - mix;
  const float l0 = mix * CL[n*3+0] + im * a0;
  const float l1 = mix * CL[n*3+1] + im * a1;
  const float l2 = mix * CL[n*3+2] + im * a2;
  const float mx = fmaxf(l0, fmaxf(l1, l2));
  const float e0 = expf(l0 - mx), e1 = expf(l1 - mx), e2 = expf(l2 - mx);
  const float inv = 1.f / (e0 + e1 + e2);
  out[n*3+0] = e0 * inv;
  out[n*3+1] = e1 * inv;
  out[n*3+2] = e2 * inv;
  float* outl = out + NROWS * 3;
  outl[n*3+0] = l0;
  outl[n*3+1] = l1;
  outl[n*3+2] = l2;
}

extern "C" void kernel_launch(void* const* d_in, const int* in_sizes, int n_in,
                              void* d_out, int out_size, void* d_ws, size_t ws_size,
                              hipStream_t stream) {
  const float* H     = (const float*)d_in[0];
  const float* Wc    = (const float*)d_in[1];
  const float* bc    = (const float*)d_in[2];
  const float* W1    = (const float*)d_in[3];
  const float* b1    = (const float*)d_in[4];
  const float* W2    = (const float*)d_in[5];
  const float* b2    = (const float*)d_in[6];
  const float* alpha = (const float*)d_in[7];
  float* out = (float*)d_out;

  char* ws = (char*)d_ws;
  u16*   F        = (u16*)ws;                               // 16 MiB
  float* CL       = (float*)(ws + 16777216);                // 96 KiB
  float* partials = (float*)(ws + 16777216 + 98304);        // 2 MiB

  k_rowprep<<<NROWS, 256, 0, stream>>>(H, Wc, bc, F, CL);
  dim3 g2(64, 8);
  k_simtopk<<<g2, 256, 0, stream>>>(F, partials);
  k_finalize<<<NROWS / 256, 256, 0, stream>>>(partials, CL, W1, b1, W2, b2, alpha, out);
}